// Round 10
// baseline (258.810 us; speedup 1.0000x reference)
//
#include <hip/hip_runtime.h>
#include <math.h>

#define B_ 4
#define S_ 1024
#define E_ 1024
#define H_ 16
#define HD_ 64

typedef float4 f4;
typedef __bf16 bf16x8 __attribute__((ext_vector_type(8)));
typedef _Float16 f16x8 __attribute__((ext_vector_type(8)));
typedef ushort u16x8 __attribute__((ext_vector_type(8)));
typedef float f32x4 __attribute__((ext_vector_type(4)));

// async global->LDS, 16B per lane. LDS dest = wave-uniform base + lane*16.
__device__ __forceinline__ void gl16(const void* g, void* l) {
  __builtin_amdgcn_global_load_lds(
      (__attribute__((address_space(1))) void*)g,
      (__attribute__((address_space(3))) void*)l, 16, 0, 0);
}

template <int MT> __device__ __forceinline__ ushort cvt_hi(float x) {
  if constexpr (MT == 0) return __builtin_bit_cast(ushort, (__bf16)x);
  else return __builtin_bit_cast(ushort, (_Float16)x);
}
template <int MT> __device__ __forceinline__ float cvt_back(ushort h) {
  if constexpr (MT == 0) {
    union { unsigned u; float f; } v; v.u = (unsigned)h << 16; return v.f;
  } else {
    return (float)__builtin_bit_cast(_Float16, h);
  }
}
template <int MT> __device__ __forceinline__ f32x4 mfma_t(u16x8 a, u16x8 b, f32x4 c) {
  if constexpr (MT == 0)
    return __builtin_amdgcn_mfma_f32_16x16x32_bf16(
        __builtin_bit_cast(bf16x8, a), __builtin_bit_cast(bf16x8, b), c, 0, 0, 0);
  else
    return __builtin_amdgcn_mfma_f32_16x16x32_f16(
        __builtin_bit_cast(f16x8, a), __builtin_bit_cast(f16x8, b), c, 0, 0, 0);
}
// frag load from swizzled LDS: 16B at (row, chunk), chunk XOR row&7.
__device__ __forceinline__ u16x8 ldfrag(const ushort* s, int row, int chunk) {
  return *reinterpret_cast<const u16x8*>(s + row * 64 + ((chunk ^ (row & 7)) << 3));
}

// ws16 layout (units of MSZ = 1M ushorts = 2 MB):
// 0:Wqf  1:Wkh 2:Wkl  3:Wvf 4:Wof  5..8:xf  9..12:xbh 13..16:xbl
// 17..20:qh  21..24:kh 25..28:kl  29..32:vt  33..36:aoh

// ---------------------------------------------------------------------------
// prep_x: x fp32 -> fp16 (Q/V path) + bf16 hi/lo (K path, denorm-safe splits)
// ---------------------------------------------------------------------------
__global__ __launch_bounds__(256) void prep_x(
    const float* __restrict__ x, ushort* __restrict__ xf,
    ushort* __restrict__ xbh, ushort* __restrict__ xbl)
{
  const size_t i = ((size_t)blockIdx.x * 256 + threadIdx.x) * 8;
  float v[8];
  *reinterpret_cast<f4*>(v)     = *reinterpret_cast<const f4*>(x + i);
  *reinterpret_cast<f4*>(v + 4) = *reinterpret_cast<const f4*>(x + i + 4);
  unsigned fw[4], hw[4], lw[4];
#pragma unroll
  for (int p = 0; p < 4; ++p) {
    const float a = v[2 * p], b = v[2 * p + 1];
    fw[p] = (unsigned)cvt_hi<1>(a) | ((unsigned)cvt_hi<1>(b) << 16);
    const ushort ha = cvt_hi<0>(a), hb = cvt_hi<0>(b);
    hw[p] = (unsigned)ha | ((unsigned)hb << 16);
    lw[p] = (unsigned)cvt_hi<0>(a - cvt_back<0>(ha)) |
            ((unsigned)cvt_hi<0>(b - cvt_back<0>(hb)) << 16);
  }
  *reinterpret_cast<uint4*>(xf + i)  = make_uint4(fw[0], fw[1], fw[2], fw[3]);
  *reinterpret_cast<uint4*>(xbh + i) = make_uint4(hw[0], hw[1], hw[2], hw[3]);
  *reinterpret_cast<uint4*>(xbl + i) = make_uint4(lw[0], lw[1], lw[2], lw[3]);
}

// ---------------------------------------------------------------------------
// prep_w: W fp32 [k][n] -> transposed Wt[n][k]: Wq/Wv/Wo fp16; Wk bf16 hi/lo.
// ---------------------------------------------------------------------------
__global__ __launch_bounds__(256) void prep_w(
    const float* __restrict__ Wq, const float* __restrict__ Wk,
    const float* __restrict__ Wv, const float* __restrict__ Wo,
    ushort* __restrict__ ws16)
{
  const int MSZ = 1024 * 1024;
  const int mat = blockIdx.z;
  const int n0 = blockIdx.x * 64, k0 = blockIdx.y * 64;
  const float* W = mat == 0 ? Wq : mat == 1 ? Wk : mat == 2 ? Wv : Wo;
  ushort* Oh = ws16 + (mat == 0 ? 0 : mat == 1 ? 1 : mat == 2 ? 3 : 4) * MSZ;
  ushort* Ol = mat == 1 ? ws16 + 2 * MSZ : nullptr;

  __shared__ __align__(16) float tile[64][65];
  const int t = threadIdx.x;
  const int r = t >> 2, cq = t & 3;
#pragma unroll
  for (int j = 0; j < 4; ++j) {
    const f4 v = *reinterpret_cast<const f4*>(&W[(size_t)(k0 + r) * 1024 + n0 + cq * 16 + 4 * j]);
    tile[r][cq * 16 + 4 * j + 0] = v.x;
    tile[r][cq * 16 + 4 * j + 1] = v.y;
    tile[r][cq * 16 + 4 * j + 2] = v.z;
    tile[r][cq * 16 + 4 * j + 3] = v.w;
  }
  __syncthreads();
  unsigned hw[8], lw[8];
#pragma unroll
  for (int p = 0; p < 8; ++p) {
    const float a = tile[cq * 16 + 2 * p][r];
    const float b = tile[cq * 16 + 2 * p + 1][r];
    if (mat == 1) {
      const ushort ha = cvt_hi<0>(a), hb = cvt_hi<0>(b);
      hw[p] = (unsigned)ha | ((unsigned)hb << 16);
      lw[p] = (unsigned)cvt_hi<0>(a - cvt_back<0>(ha)) |
              ((unsigned)cvt_hi<0>(b - cvt_back<0>(hb)) << 16);
    } else {
      hw[p] = (unsigned)cvt_hi<1>(a) | ((unsigned)cvt_hi<1>(b) << 16);
    }
  }
  ushort* dh = Oh + (size_t)(n0 + r) * 1024 + k0 + cq * 16;
  *reinterpret_cast<uint4*>(dh)     = make_uint4(hw[0], hw[1], hw[2], hw[3]);
  *reinterpret_cast<uint4*>(dh + 8) = make_uint4(hw[4], hw[5], hw[6], hw[7]);
  if (Ol) {
    ushort* dl = Ol + (size_t)(n0 + r) * 1024 + k0 + cq * 16;
    *reinterpret_cast<uint4*>(dl)     = make_uint4(lw[0], lw[1], lw[2], lw[3]);
    *reinterpret_cast<uint4*>(dl + 8) = make_uint4(lw[4], lw[5], lw[6], lw[7]);
  }
}

// ---------------------------------------------------------------------------
// MFMA GEMM (R6 structure, single-buffered): C = A @ Wt^T + bias.
// Tile 64(M) x 128(N), BK=64. All staging via global_load_lds.
// ---------------------------------------------------------------------------
template <int TERMS, int MT, int OMODE>
__global__ __launch_bounds__(256) void gemm_mfma(
    const ushort* __restrict__ Ab, const ushort* __restrict__ Abl,
    const ushort* __restrict__ Bhg, const ushort* __restrict__ Blg,
    const float* __restrict__ bias, float scale,
    ushort* __restrict__ Oh, ushort* __restrict__ Ol, float* __restrict__ Of)
{
  const int n0 = blockIdx.x * 128;
  const int m0 = blockIdx.y * 64;
  const int t = threadIdx.x;
  const int wv = t >> 6, lane = t & 63;
  const int lr = lane & 15, lg = lane >> 4;
  const int wm = (wv >> 1) * 32, wn = (wv & 1) * 64;
  const int row8 = lane >> 3, ch8 = lane & 7;

  __shared__ __align__(16) ushort Ah_s[64 * 64];
  __shared__ __align__(16) ushort Al_s[TERMS == 3 ? 64 * 64 : 16];
  __shared__ __align__(16) ushort Bh_s[128 * 64];
  __shared__ __align__(16) ushort Bl_s[TERMS == 3 ? 128 * 64 : 16];
  __shared__ __align__(16) ushort tr_s[OMODE == 2 ? 128 * 72 : 16];

  f32x4 acc[2][4];
#pragma unroll
  for (int mi = 0; mi < 2; ++mi)
#pragma unroll
    for (int ni = 0; ni < 4; ++ni) { f32x4 z = {0.f, 0.f, 0.f, 0.f}; acc[mi][ni] = z; }

  for (int kt = 0; kt < 16; ++kt) {
    const int k0 = kt * 64;
    __syncthreads();
#pragma unroll
    for (int j = 0; j < 4; ++j) {
      const int row = wv * 32 + j * 8 + row8;
      const size_t go = (size_t)(n0 + row) * 1024 + k0 + ((ch8 ^ (row & 7)) << 3);
      gl16(Bhg + go, &Bh_s[(wv * 32 + j * 8) * 64]);
      if constexpr (TERMS == 3) gl16(Blg + go, &Bl_s[(wv * 32 + j * 8) * 64]);
    }
#pragma unroll
    for (int j = 0; j < 2; ++j) {
      const int row = wv * 16 + j * 8 + row8;
      const size_t go = (size_t)(m0 + row) * 1024 + k0 + ((ch8 ^ (row & 7)) << 3);
      gl16(Ab + go, &Ah_s[(wv * 16 + j * 8) * 64]);
      if constexpr (TERMS == 3) gl16(Abl + go, &Al_s[(wv * 16 + j * 8) * 64]);
    }
    __syncthreads();
#pragma unroll
    for (int ks = 0; ks < 2; ++ks) {
      const u16x8 ah0 = ldfrag(Ah_s, wm + lr, ks * 4 + lg);
      const u16x8 ah1 = ldfrag(Ah_s, wm + 16 + lr, ks * 4 + lg);
      u16x8 al0, al1;
      if constexpr (TERMS == 3) {
        al0 = ldfrag(Al_s, wm + lr, ks * 4 + lg);
        al1 = ldfrag(Al_s, wm + 16 + lr, ks * 4 + lg);
      }
#pragma unroll
      for (int ni = 0; ni < 4; ++ni) {
        const u16x8 bh = ldfrag(Bh_s, wn + ni * 16 + lr, ks * 4 + lg);
        acc[0][ni] = mfma_t<MT>(ah0, bh, acc[0][ni]);
        acc[1][ni] = mfma_t<MT>(ah1, bh, acc[1][ni]);
        if constexpr (TERMS == 3) {
          const u16x8 bl = ldfrag(Bl_s, wn + ni * 16 + lr, ks * 4 + lg);
          acc[0][ni] = mfma_t<MT>(ah0, bl, acc[0][ni]);
          acc[1][ni] = mfma_t<MT>(ah1, bl, acc[1][ni]);
          acc[0][ni] = mfma_t<MT>(al0, bh, acc[0][ni]);
          acc[1][ni] = mfma_t<MT>(al1, bh, acc[1][ni]);
        }
      }
    }
  }

  // ---- epilogue ----
  if constexpr (OMODE == 2) {
    __syncthreads();
#pragma unroll
    for (int mi = 0; mi < 2; ++mi)
#pragma unroll
      for (int ni = 0; ni < 4; ++ni)
#pragma unroll
        for (int r = 0; r < 4; ++r) {
          const int n_l = wn + ni * 16 + lr, m_l = wm + mi * 16 + lg * 4 + r;
          tr_s[n_l * 72 + m_l] = cvt_hi<1>(acc[mi][ni][r] + bias[n0 + n_l]);
        }
    __syncthreads();
    const int row = t >> 1, hf = t & 1;
    const int n_g = n0 + row;
    const int h_ = n_g >> 6, hd = n_g & 63;
    const int b_g = m0 >> 10;
    ushort* dst = Oh + ((size_t)(b_g * 16 + h_) * 64 + hd) * 1024 + (m0 & 1023) + hf * 32;
#pragma unroll
    for (int j = 0; j < 4; ++j)
      *reinterpret_cast<uint4*>(dst + 8 * j) =
          *reinterpret_cast<const uint4*>(&tr_s[row * 72 + hf * 32 + 8 * j]);
  } else {
#pragma unroll
    for (int mi = 0; mi < 2; ++mi)
#pragma unroll
      for (int ni = 0; ni < 4; ++ni) {
        const int n = n0 + wn + ni * 16 + lr;
        const float bi = bias[n];
#pragma unroll
        for (int r = 0; r < 4; ++r) {
          const int m = m0 + wm + mi * 16 + lg * 4 + r;
          const float v = (acc[mi][ni][r] + bi) * scale;
          if constexpr (OMODE == 0) {
            Of[(size_t)m * 1024 + n] = v;
          } else {
            const size_t addr =
                ((size_t)((m >> 10) * 16 + (n >> 6)) * 1024 + (m & 1023)) * 64 + (n & 63);
            if constexpr (OMODE == 1) {
              const _Float16 hv = (_Float16)v;
              Oh[addr] = __builtin_bit_cast(ushort, hv);
              Ol[addr] = cvt_hi<1>(v - (float)hv);
            } else {  // OMODE == 3
              Oh[addr] = cvt_hi<1>(v);
            }
          }
        }
      }
  }
}

// ---------------------------------------------------------------------------
// MFMA dual-softmax attention (R6 math/geometry; prefetch restructure):
// block = (bh, 64 q-rows), 4 waves, 1024 blocks, 4 blocks/CU.
// Pass 1: K-hi double-buffered, stage(kt+1) before compute(kt), 1 barrier/kt.
// Pass 2: kh+vt double-buffered (LDS 40KB total -> occupancy kept), K-lo
//         direct global->reg (L2-resident, 8x16B issued early), 1 barrier/kt;
//         weight stores get the PV+stage phase to retire before the drain.
// Values fed to MFMA/exp identical to R6 -> bit-identical output.
// ---------------------------------------------------------------------------
__global__ __launch_bounds__(256) void attn_mfma(
    const ushort* __restrict__ qh_g, const ushort* __restrict__ kh_g,
    const ushort* __restrict__ kl_g, const ushort* __restrict__ vt_g,
    const float* __restrict__ ge, float* __restrict__ attn,
    ushort* __restrict__ aoh)
{
  __shared__ __align__(16) ushort kh2_s[2][4096];
  __shared__ __align__(16) ushort vt2_s[2][4096];
  __shared__ __align__(16) ushort w_s[4][1024];

  const int bid = blockIdx.x;
  const int wg = (bid & 7) * 128 + (bid >> 3);  // bijective XCD swizzle (1024 = 8*128)
  const int bh = wg >> 4, qb = wg & 15;
  const int b = bh >> 4, h = bh & 15;

  const int t = threadIdx.x;
  const int wv = t >> 6, lane = t & 63;
  const int lr = lane & 15, lg = lane >> 4;
  const int row8 = lane >> 3, ch8 = lane & 7;
  const int q0 = qb * 64 + wv * 16;
  const int doff = lg * 8;

  // Q (fp16, pre-scaled 0.125) + G (fp32 kept for u; fp16-hi for pass 1)
  u16x8 qh[2], gh[2];
  float gf[2][8];
#pragma unroll
  for (int ks = 0; ks < 2; ++ks) {
    const size_t qoff = ((size_t)bh * S_ + q0 + lr) * HD_ + ks * 32 + lg * 8;
    qh[ks] = *reinterpret_cast<const u16x8*>(qh_g + qoff);
    const float* grow = ge + ((size_t)b * S_ + q0 + lr) * HD_ + ks * 32 + lg * 8;
    *reinterpret_cast<f4*>(&gf[ks][0]) = *reinterpret_cast<const f4*>(grow);
    *reinterpret_cast<f4*>(&gf[ks][4]) = *reinterpret_cast<const f4*>(grow + 4);
#pragma unroll
    for (int e = 0; e < 8; ++e) gh[ks][e] = cvt_hi<1>(gf[ks][e]);
  }

  const ushort* khb = kh_g + (size_t)bh * S_ * HD_;
  const ushort* klb = kl_g + (size_t)bh * S_ * HD_;
  const ushort* vtb = vt_g + (size_t)bh * HD_ * S_;

  float z1L[4] = {0.f, 0.f, 0.f, 0.f}, z2L[4] = {0.f, 0.f, 0.f, 0.f};

  // ---------------- pass 1: z-sums (K-hi only), dbuf prefetch ----------------
  {
    auto stageK = [&](int kt, int c) {
#pragma unroll
      for (int j = 0; j < 2; ++j) {
        const int row = wv * 16 + j * 8 + row8;
        gl16(khb + kt * 4096 + row * 64 + (((ch8) ^ (row & 7)) << 3),
             &kh2_s[c][(wv * 16 + j * 8) * 64]);
      }
    };
    stageK(0, 0);
    __syncthreads();
    for (int kt = 0; kt < 16; ++kt) {
      if (kt < 15) stageK(kt + 1, (kt + 1) & 1);
      const ushort* kp = kh2_s[kt & 1];
      f32x4 s1[4], s2[4];
#pragma unroll
      for (int ct = 0; ct < 4; ++ct) {
        f32x4 z = {0.f, 0.f, 0.f, 0.f};
        s1[ct] = z; s2[ct] = z;
#pragma unroll
        for (int ks = 0; ks < 2; ++ks) {
          const u16x8 khf = ldfrag(kp, ct * 16 + lr, ks * 4 + lg);
          s1[ct] = mfma_t<1>(qh[ks], khf, s1[ct]);
          s2[ct] = mfma_t<1>(gh[ks], khf, s2[ct]);
        }
      }
#pragma unroll
      for (int r = 0; r < 4; ++r)
#pragma unroll
        for (int ct = 0; ct < 4; ++ct) {
          z1L[r] += __expf(s1[ct][r] - 16.f);
          z2L[r] += __expf(s2[ct][r] - 64.f);
        }
      __syncthreads();
    }
  }

  float rzr[4];
#pragma unroll
  for (int r = 0; r < 4; ++r) {
    float z1 = z1L[r], z2 = z2L[r];
#pragma unroll
    for (int msk = 1; msk < 16; msk <<= 1) {
      z1 += __shfl_xor(z1, msk);
      z2 += __shfl_xor(z2, msk);
    }
    rzr[r] = 1.f / (z1 * z2);
  }

  // u = q + g, fp16 hi/lo split
  u16x8 uh[2], ul[2];
#pragma unroll
  for (int ks = 0; ks < 2; ++ks)
#pragma unroll
    for (int e = 0; e < 8; ++e) {
      const float u = cvt_back<1>(qh[ks][e]) + gf[ks][e];
      const _Float16 hu = (_Float16)u;
      uh[ks][e] = __builtin_bit_cast(ushort, hu);
      ul[ks][e] = cvt_hi<1>(u - (float)hu);
    }

  f32x4 o[4];
#pragma unroll
  for (int dt = 0; dt < 4; ++dt) { f32x4 z = {0.f, 0.f, 0.f, 0.f}; o[dt] = z; }

  float* wrow = attn + ((size_t)bh * S_ + q0) * S_;
  ushort* wsw = w_s[wv];

  // ---------------- pass 2: exact weights + PV, dbuf kh/vt + kl-direct ------
  {
    auto stageKV = [&](int kt, int c) {
#pragma unroll
      for (int j = 0; j < 2; ++j) {
        const int row = wv * 16 + j * 8 + row8;
        const int sw = (ch8 ^ (row & 7)) << 3;
        const int ldso = (wv * 16 + j * 8) * 64;
        gl16(khb + kt * 4096 + row * 64 + sw, &kh2_s[c][ldso]);
        gl16(vtb + kt * 64 + (size_t)row * 1024 + sw, &vt2_s[c][ldso]);
      }
    };
    stageKV(0, 0);
    __syncthreads();
    for (int kt = 0; kt < 16; ++kt) {
      if (kt < 15) stageKV(kt + 1, (kt + 1) & 1);
      const ushort* khp = kh2_s[kt & 1];
      const ushort* vtp = vt2_s[kt & 1];

      // K-lo fragments direct from global (L2-resident); issued early,
      // first consumed after the hh/lh MFMA chain -> latency covered.
      u16x8 klr[4][2];
#pragma unroll
      for (int ct = 0; ct < 4; ++ct) {
        const int key = kt * 64 + ct * 16 + lr;
#pragma unroll
        for (int ks = 0; ks < 2; ++ks)
          klr[ct][ks] = *reinterpret_cast<const u16x8*>(
              klb + (size_t)key * HD_ + ks * 32 + doff);
      }

      f32x4 s12[4];
#pragma unroll
      for (int ct = 0; ct < 4; ++ct) {
        f32x4 z = {0.f, 0.f, 0.f, 0.f};
        s12[ct] = z;
#pragma unroll
        for (int ks = 0; ks < 2; ++ks) {
          const u16x8 khf = ldfrag(khp, ct * 16 + lr, ks * 4 + lg);
          s12[ct] = mfma_t<1>(uh[ks], khf, s12[ct]);
          s12[ct] = mfma_t<1>(uh[ks], klr[ct][ks], s12[ct]);
          s12[ct] = mfma_t<1>(ul[ks], khf, s12[ct]);
        }
      }
      // weights -> wave-private LDS (fp16, swizzled)
#pragma unroll
      for (int ct = 0; ct < 4; ++ct) {
#pragma unroll
        for (int r = 0; r < 4; ++r) {
          const int rowq = lg * 4 + r;
          const int key = ct * 16 + lr;
          const float wv2 = __expf(s12[ct][r] - 80.f) * rzr[r];
          const int ch = (key >> 3) ^ (rowq & 7);
          wsw[rowq * 64 + ch * 8 + (key & 7)] = cvt_hi<1>(wv2);
        }
      }
      // global fp32 weight store via own-wave LDS transpose (x4 vectorized)
      {
        const int rowq = (lane >> 2) & 15, c = lane & 3;
#pragma unroll
        for (int j = 0; j < 2; ++j) {
          const int key8 = c * 16 + j * 8;
          const int ch = (key8 >> 3) ^ (rowq & 7);
          const uint4 wb = *reinterpret_cast<const uint4*>(&wsw[rowq * 64 + ch * 8]);
          const ushort* wp = reinterpret_cast<const ushort*>(&wb);
          float* dst = wrow + (size_t)rowq * S_ + kt * 64 + key8;
          *reinterpret_cast<f4*>(dst) = make_float4(
              cvt_back<1>(wp[0]), cvt_back<1>(wp[1]), cvt_back<1>(wp[2]), cvt_back<1>(wp[3]));
          *reinterpret_cast<f4*>(dst + 4) = make_float4(
              cvt_back<1>(wp[4]), cvt_back<1>(wp[5]), cvt_back<1>(wp[6]), cvt_back<1>(wp[7]));
        }
      }
      // PV (reads own-wave w_s + block-shared vt tile)
#pragma unroll
      for (int ks = 0; ks < 2; ++ks) {
        const u16x8 af = ldfrag(wsw, lr, ks * 4 + lg);
#pragma unroll
        for (int dt = 0; dt < 4; ++dt) {
          const u16x8 vf = ldfrag(vtp, dt * 16 + lr, ks * 4 + lg);
          o[dt] = mfma_t<1>(af, vf, o[dt]);
        }
      }
      __syncthreads();
    }
  }

  // epilogue: ao[b][s][e] fp16
#pragma unroll
  for (int dt = 0; dt < 4; ++dt)
#pragma unroll
    for (int r = 0; r < 4; ++r)
      aoh[((size_t)b * S_ + q0 + lg * 4 + r) * E_ + h * 64 + dt * 16 + lr] =
          cvt_hi<1>(o[dt][r]);
}

extern "C" void kernel_launch(void* const* d_in, const int* in_sizes, int n_in,
                              void* d_out, int out_size, void* d_ws, size_t ws_size,
                              hipStream_t stream) {
  const float* x  = (const float*)d_in[0];
  const float* ge = (const float*)d_in[1];
  const float* Wq = (const float*)d_in[2];
  const float* bq = (const float*)d_in[3];
  const float* Wk = (const float*)d_in[4];
  const float* bk = (const float*)d_in[5];
  const float* Wv = (const float*)d_in[6];
  const float* bv = (const float*)d_in[7];
  const float* Wo = (const float*)d_in[8];
  const float* bo = (const float*)d_in[9];

  float* out  = (float*)d_out;
  float* attn = out + (size_t)B_ * S_ * E_;

  const size_t MSZ = 1024 * 1024;
  ushort* ws16 = (ushort*)d_ws;  // ~74 MB used (ws ~1 GiB per fill counters)
  ushort* Wqf = ws16 + 0 * MSZ;
  ushort* Wkh = ws16 + 1 * MSZ;
  ushort* Wkl = ws16 + 2 * MSZ;
  ushort* Wvf = ws16 + 3 * MSZ;
  ushort* Wof = ws16 + 4 * MSZ;
  ushort* xf  = ws16 + 5 * MSZ;   // fp16 x
  ushort* xbh = ws16 + 9 * MSZ;   // bf16 x hi
  ushort* xbl = ws16 + 13 * MSZ;  // bf16 x lo
  ushort* qh  = ws16 + 17 * MSZ;  // fp16 q (single, pre-scaled) [B,H,S,HD]
  ushort* kh  = ws16 + 21 * MSZ;  // fp16 k hi [B,H,S,HD]
  ushort* kl  = ws16 + 25 * MSZ;  // fp16 k lo
  ushort* vt  = ws16 + 29 * MSZ;  // fp16 v [B,H,HD,S]
  ushort* aoh = ws16 + 33 * MSZ;  // fp16 ao [B,S,E]

  dim3 blk(256);
  hipLaunchKernelGGL(prep_x, dim3(2048), blk, 0, stream, x, xf, xbh, xbl);
  hipLaunchKernelGGL(prep_w, dim3(16, 16, 4), blk, 0, stream, Wq, Wk, Wv, Wo, ws16);

  dim3 ggrid(E_ / 128, (B_ * S_) / 64);
  // Q: 1-term fp16 (pre-scaled 0.125)
  hipLaunchKernelGGL((gemm_mfma<1, 1, 3>), ggrid, blk, 0, stream,
                     xf, nullptr, Wqf, nullptr, bq, 0.125f, qh, nullptr, nullptr);
  // K: 3-term bf16 (denorm-safe splits), output fp16 hi/lo
  hipLaunchKernelGGL((gemm_mfma<3, 0, 1>), ggrid, blk, 0, stream,
                     xbh, xbl, Wkh, Wkl, bk, 1.0f, kh, kl, nullptr);
  // V: 1-term fp16, transposed output
  hipLaunchKernelGGL((gemm_mfma<1, 1, 2>), ggrid, blk, 0, stream,
                     xf, nullptr, Wvf, nullptr, bv, 1.0f, vt, nullptr, nullptr);

  hipLaunchKernelGGL(attn_mfma, dim3(1024), blk, 0, stream,
                     qh, kh, kl, vt, ge, attn, aoh);

  // O: 1-term fp16 -> fp32 out
  hipLaunchKernelGGL((gemm_mfma<1, 1, 0>), ggrid, blk, 0, stream,
                     aoh, nullptr, Wof, nullptr, bo, 1.0f, nullptr, nullptr, out);
}

// Round 11
// 239.755 us; speedup vs baseline: 1.0795x; 1.0795x over previous
//
#include <hip/hip_runtime.h>
#include <math.h>

#define B_ 4
#define S_ 1024
#define E_ 1024
#define H_ 16
#define HD_ 64

typedef float4 f4;
typedef __bf16 bf16x8 __attribute__((ext_vector_type(8)));
typedef _Float16 f16x8 __attribute__((ext_vector_type(8)));
typedef ushort u16x8 __attribute__((ext_vector_type(8)));
typedef float f32x4 __attribute__((ext_vector_type(4)));

// async global->LDS, 16B per lane. LDS dest = wave-uniform base + lane*16.
__device__ __forceinline__ void gl16(const void* g, void* l) {
  __builtin_amdgcn_global_load_lds(
      (__attribute__((address_space(1))) void*)g,
      (__attribute__((address_space(3))) void*)l, 16, 0, 0);
}

template <int MT> __device__ __forceinline__ ushort cvt_hi(float x) {
  if constexpr (MT == 0) return __builtin_bit_cast(ushort, (__bf16)x);
  else return __builtin_bit_cast(ushort, (_Float16)x);
}
template <int MT> __device__ __forceinline__ float cvt_back(ushort h) {
  if constexpr (MT == 0) {
    union { unsigned u; float f; } v; v.u = (unsigned)h << 16; return v.f;
  } else {
    return (float)__builtin_bit_cast(_Float16, h);
  }
}
template <int MT> __device__ __forceinline__ f32x4 mfma_t(u16x8 a, u16x8 b, f32x4 c) {
  if constexpr (MT == 0)
    return __builtin_amdgcn_mfma_f32_16x16x32_bf16(
        __builtin_bit_cast(bf16x8, a), __builtin_bit_cast(bf16x8, b), c, 0, 0, 0);
  else
    return __builtin_amdgcn_mfma_f32_16x16x32_f16(
        __builtin_bit_cast(f16x8, a), __builtin_bit_cast(f16x8, b), c, 0, 0, 0);
}
// frag load from swizzled LDS: 16B at (row, chunk), chunk XOR row&7.
__device__ __forceinline__ u16x8 ldfrag(const ushort* s, int row, int chunk) {
  return *reinterpret_cast<const u16x8*>(s + row * 64 + ((chunk ^ (row & 7)) << 3));
}

// ws16 layout (units of MSZ = 1M ushorts = 2 MB):
// 0:Wqf  1:Wkh 2:Wkl  3:Wvf 4:Wof  5..8:xf  9..12:xbh 13..16:xbl
// 17..20:qh  21..24:kh 25..28:kl  29..32:vt  33..36:aoh

// ---------------------------------------------------------------------------
// prep_x: x fp32 -> fp16 (Q/V path) + bf16 hi/lo (K path, denorm-safe splits)
// ---------------------------------------------------------------------------
__global__ __launch_bounds__(256) void prep_x(
    const float* __restrict__ x, ushort* __restrict__ xf,
    ushort* __restrict__ xbh, ushort* __restrict__ xbl)
{
  const size_t i = ((size_t)blockIdx.x * 256 + threadIdx.x) * 8;
  float v[8];
  *reinterpret_cast<f4*>(v)     = *reinterpret_cast<const f4*>(x + i);
  *reinterpret_cast<f4*>(v + 4) = *reinterpret_cast<const f4*>(x + i + 4);
  unsigned fw[4], hw[4], lw[4];
#pragma unroll
  for (int p = 0; p < 4; ++p) {
    const float a = v[2 * p], b = v[2 * p + 1];
    fw[p] = (unsigned)cvt_hi<1>(a) | ((unsigned)cvt_hi<1>(b) << 16);
    const ushort ha = cvt_hi<0>(a), hb = cvt_hi<0>(b);
    hw[p] = (unsigned)ha | ((unsigned)hb << 16);
    lw[p] = (unsigned)cvt_hi<0>(a - cvt_back<0>(ha)) |
            ((unsigned)cvt_hi<0>(b - cvt_back<0>(hb)) << 16);
  }
  *reinterpret_cast<uint4*>(xf + i)  = make_uint4(fw[0], fw[1], fw[2], fw[3]);
  *reinterpret_cast<uint4*>(xbh + i) = make_uint4(hw[0], hw[1], hw[2], hw[3]);
  *reinterpret_cast<uint4*>(xbl + i) = make_uint4(lw[0], lw[1], lw[2], lw[3]);
}

// ---------------------------------------------------------------------------
// prep_w: W fp32 [k][n] -> transposed Wt[n][k]: Wq/Wv/Wo fp16; Wk bf16 hi/lo.
// ---------------------------------------------------------------------------
__global__ __launch_bounds__(256) void prep_w(
    const float* __restrict__ Wq, const float* __restrict__ Wk,
    const float* __restrict__ Wv, const float* __restrict__ Wo,
    ushort* __restrict__ ws16)
{
  const int MSZ = 1024 * 1024;
  const int mat = blockIdx.z;
  const int n0 = blockIdx.x * 64, k0 = blockIdx.y * 64;
  const float* W = mat == 0 ? Wq : mat == 1 ? Wk : mat == 2 ? Wv : Wo;
  ushort* Oh = ws16 + (mat == 0 ? 0 : mat == 1 ? 1 : mat == 2 ? 3 : 4) * MSZ;
  ushort* Ol = mat == 1 ? ws16 + 2 * MSZ : nullptr;

  __shared__ __align__(16) float tile[64][65];
  const int t = threadIdx.x;
  const int r = t >> 2, cq = t & 3;
#pragma unroll
  for (int j = 0; j < 4; ++j) {
    const f4 v = *reinterpret_cast<const f4*>(&W[(size_t)(k0 + r) * 1024 + n0 + cq * 16 + 4 * j]);
    tile[r][cq * 16 + 4 * j + 0] = v.x;
    tile[r][cq * 16 + 4 * j + 1] = v.y;
    tile[r][cq * 16 + 4 * j + 2] = v.z;
    tile[r][cq * 16 + 4 * j + 3] = v.w;
  }
  __syncthreads();
  unsigned hw[8], lw[8];
#pragma unroll
  for (int p = 0; p < 8; ++p) {
    const float a = tile[cq * 16 + 2 * p][r];
    const float b = tile[cq * 16 + 2 * p + 1][r];
    if (mat == 1) {
      const ushort ha = cvt_hi<0>(a), hb = cvt_hi<0>(b);
      hw[p] = (unsigned)ha | ((unsigned)hb << 16);
      lw[p] = (unsigned)cvt_hi<0>(a - cvt_back<0>(ha)) |
              ((unsigned)cvt_hi<0>(b - cvt_back<0>(hb)) << 16);
    } else {
      hw[p] = (unsigned)cvt_hi<1>(a) | ((unsigned)cvt_hi<1>(b) << 16);
    }
  }
  ushort* dh = Oh + (size_t)(n0 + r) * 1024 + k0 + cq * 16;
  *reinterpret_cast<uint4*>(dh)     = make_uint4(hw[0], hw[1], hw[2], hw[3]);
  *reinterpret_cast<uint4*>(dh + 8) = make_uint4(hw[4], hw[5], hw[6], hw[7]);
  if (Ol) {
    ushort* dl = Ol + (size_t)(n0 + r) * 1024 + k0 + cq * 16;
    *reinterpret_cast<uint4*>(dl)     = make_uint4(lw[0], lw[1], lw[2], lw[3]);
    *reinterpret_cast<uint4*>(dl + 8) = make_uint4(lw[4], lw[5], lw[6], lw[7]);
  }
}

// ---------------------------------------------------------------------------
// MFMA GEMM (R6 structure, single-buffered): C = A @ Wt^T + bias.
// Tile 64(M) x 128(N), BK=64. All staging via global_load_lds.
// ---------------------------------------------------------------------------
template <int TERMS, int MT, int OMODE>
__global__ __launch_bounds__(256) void gemm_mfma(
    const ushort* __restrict__ Ab, const ushort* __restrict__ Abl,
    const ushort* __restrict__ Bhg, const ushort* __restrict__ Blg,
    const float* __restrict__ bias, float scale,
    ushort* __restrict__ Oh, ushort* __restrict__ Ol, float* __restrict__ Of)
{
  const int n0 = blockIdx.x * 128;
  const int m0 = blockIdx.y * 64;
  const int t = threadIdx.x;
  const int wv = t >> 6, lane = t & 63;
  const int lr = lane & 15, lg = lane >> 4;
  const int wm = (wv >> 1) * 32, wn = (wv & 1) * 64;
  const int row8 = lane >> 3, ch8 = lane & 7;

  __shared__ __align__(16) ushort Ah_s[64 * 64];
  __shared__ __align__(16) ushort Al_s[TERMS == 3 ? 64 * 64 : 16];
  __shared__ __align__(16) ushort Bh_s[128 * 64];
  __shared__ __align__(16) ushort Bl_s[TERMS == 3 ? 128 * 64 : 16];
  __shared__ __align__(16) ushort tr_s[OMODE == 2 ? 128 * 72 : 16];

  f32x4 acc[2][4];
#pragma unroll
  for (int mi = 0; mi < 2; ++mi)
#pragma unroll
    for (int ni = 0; ni < 4; ++ni) { f32x4 z = {0.f, 0.f, 0.f, 0.f}; acc[mi][ni] = z; }

  for (int kt = 0; kt < 16; ++kt) {
    const int k0 = kt * 64;
    __syncthreads();
#pragma unroll
    for (int j = 0; j < 4; ++j) {
      const int row = wv * 32 + j * 8 + row8;
      const size_t go = (size_t)(n0 + row) * 1024 + k0 + ((ch8 ^ (row & 7)) << 3);
      gl16(Bhg + go, &Bh_s[(wv * 32 + j * 8) * 64]);
      if constexpr (TERMS == 3) gl16(Blg + go, &Bl_s[(wv * 32 + j * 8) * 64]);
    }
#pragma unroll
    for (int j = 0; j < 2; ++j) {
      const int row = wv * 16 + j * 8 + row8;
      const size_t go = (size_t)(m0 + row) * 1024 + k0 + ((ch8 ^ (row & 7)) << 3);
      gl16(Ab + go, &Ah_s[(wv * 16 + j * 8) * 64]);
      if constexpr (TERMS == 3) gl16(Abl + go, &Al_s[(wv * 16 + j * 8) * 64]);
    }
    __syncthreads();
#pragma unroll
    for (int ks = 0; ks < 2; ++ks) {
      const u16x8 ah0 = ldfrag(Ah_s, wm + lr, ks * 4 + lg);
      const u16x8 ah1 = ldfrag(Ah_s, wm + 16 + lr, ks * 4 + lg);
      u16x8 al0, al1;
      if constexpr (TERMS == 3) {
        al0 = ldfrag(Al_s, wm + lr, ks * 4 + lg);
        al1 = ldfrag(Al_s, wm + 16 + lr, ks * 4 + lg);
      }
#pragma unroll
      for (int ni = 0; ni < 4; ++ni) {
        const u16x8 bh = ldfrag(Bh_s, wn + ni * 16 + lr, ks * 4 + lg);
        acc[0][ni] = mfma_t<MT>(ah0, bh, acc[0][ni]);
        acc[1][ni] = mfma_t<MT>(ah1, bh, acc[1][ni]);
        if constexpr (TERMS == 3) {
          const u16x8 bl = ldfrag(Bl_s, wn + ni * 16 + lr, ks * 4 + lg);
          acc[0][ni] = mfma_t<MT>(ah0, bl, acc[0][ni]);
          acc[1][ni] = mfma_t<MT>(ah1, bl, acc[1][ni]);
          acc[0][ni] = mfma_t<MT>(al0, bh, acc[0][ni]);
          acc[1][ni] = mfma_t<MT>(al1, bh, acc[1][ni]);
        }
      }
    }
  }

  // ---- epilogue ----
  if constexpr (OMODE == 2) {
    __syncthreads();
#pragma unroll
    for (int mi = 0; mi < 2; ++mi)
#pragma unroll
      for (int ni = 0; ni < 4; ++ni)
#pragma unroll
        for (int r = 0; r < 4; ++r) {
          const int n_l = wn + ni * 16 + lr, m_l = wm + mi * 16 + lg * 4 + r;
          tr_s[n_l * 72 + m_l] = cvt_hi<1>(acc[mi][ni][r] + bias[n0 + n_l]);
        }
    __syncthreads();
    const int row = t >> 1, hf = t & 1;
    const int n_g = n0 + row;
    const int h_ = n_g >> 6, hd = n_g & 63;
    const int b_g = m0 >> 10;
    ushort* dst = Oh + ((size_t)(b_g * 16 + h_) * 64 + hd) * 1024 + (m0 & 1023) + hf * 32;
#pragma unroll
    for (int j = 0; j < 4; ++j)
      *reinterpret_cast<uint4*>(dst + 8 * j) =
          *reinterpret_cast<const uint4*>(&tr_s[row * 72 + hf * 32 + 8 * j]);
  } else {
#pragma unroll
    for (int mi = 0; mi < 2; ++mi)
#pragma unroll
      for (int ni = 0; ni < 4; ++ni) {
        const int n = n0 + wn + ni * 16 + lr;
        const float bi = bias[n];
#pragma unroll
        for (int r = 0; r < 4; ++r) {
          const int m = m0 + wm + mi * 16 + lg * 4 + r;
          const float v = (acc[mi][ni][r] + bi) * scale;
          if constexpr (OMODE == 0) {
            Of[(size_t)m * 1024 + n] = v;
          } else {
            const size_t addr =
                ((size_t)((m >> 10) * 16 + (n >> 6)) * 1024 + (m & 1023)) * 64 + (n & 63);
            if constexpr (OMODE == 1) {
              const _Float16 hv = (_Float16)v;
              Oh[addr] = __builtin_bit_cast(ushort, hv);
              Ol[addr] = cvt_hi<1>(v - (float)hv);
            } else {  // OMODE == 3
              Oh[addr] = cvt_hi<1>(v);
            }
          }
        }
      }
  }
}

// ---------------------------------------------------------------------------
// MFMA dual-softmax attention: R6 math, counted-vmcnt pipeline (T4).
// Both passes double-buffered with RAW s_barrier + asm s_waitcnt vmcnt(N):
// prefetched loads stay in flight ACROSS barriers; we never wait on the
// weight-store stream. Per-thread vmem accounting:
//   pass1: 2 loads/kt -> vmcnt(2) (kt<15), vmcnt(0) (kt=15)
//   pass2: 6 loads + 4 stores/kt -> vmcnt(6) kt=0, vmcnt(10) mid, vmcnt(4) kt=15
// Q/G loads drained (vmcnt(0)) before the prologue so counts stay exact.
// Values fed to MFMA/exp identical to R6 -> bit-identical output.
// ---------------------------------------------------------------------------
__global__ __launch_bounds__(256) void attn_mfma(
    const ushort* __restrict__ qh_g, const ushort* __restrict__ kh_g,
    const ushort* __restrict__ kl_g, const ushort* __restrict__ vt_g,
    const float* __restrict__ ge, float* __restrict__ attn,
    ushort* __restrict__ aoh)
{
  __shared__ __align__(16) ushort kh2_s[2][4096];
  __shared__ __align__(16) ushort kl2_s[2][4096];
  __shared__ __align__(16) ushort vt2_s[2][4096];
  __shared__ __align__(16) ushort w_s[4][1024];

  const int bid = blockIdx.x;
  const int wg = (bid & 7) * 128 + (bid >> 3);  // bijective XCD swizzle (1024 = 8*128)
  const int bh = wg >> 4, qb = wg & 15;
  const int b = bh >> 4, h = bh & 15;

  const int t = threadIdx.x;
  const int wv = t >> 6, lane = t & 63;
  const int lr = lane & 15, lg = lane >> 4;
  const int row8 = lane >> 3, ch8 = lane & 7;
  const int q0 = qb * 64 + wv * 16;

  // Q (fp16, pre-scaled 0.125) + G (fp32 kept for u; fp16-hi for pass 1)
  u16x8 qh[2], gh[2];
  float gf[2][8];
#pragma unroll
  for (int ks = 0; ks < 2; ++ks) {
    const size_t qoff = ((size_t)bh * S_ + q0 + lr) * HD_ + ks * 32 + lg * 8;
    qh[ks] = *reinterpret_cast<const u16x8*>(qh_g + qoff);
    const float* grow = ge + ((size_t)b * S_ + q0 + lr) * HD_ + ks * 32 + lg * 8;
    *reinterpret_cast<f4*>(&gf[ks][0]) = *reinterpret_cast<const f4*>(grow);
    *reinterpret_cast<f4*>(&gf[ks][4]) = *reinterpret_cast<const f4*>(grow + 4);
#pragma unroll
    for (int e = 0; e < 8; ++e) gh[ks][e] = cvt_hi<1>(gf[ks][e]);
  }

  const ushort* khb = kh_g + (size_t)bh * S_ * HD_;
  const ushort* klb = kl_g + (size_t)bh * S_ * HD_;
  const ushort* vtb = vt_g + (size_t)bh * HD_ * S_;

  auto stageK = [&](int kt, int c) {
#pragma unroll
    for (int j = 0; j < 2; ++j) {
      const int row = wv * 16 + j * 8 + row8;
      gl16(khb + kt * 4096 + row * 64 + ((ch8 ^ (row & 7)) << 3),
           &kh2_s[c][(wv * 16 + j * 8) * 64]);
    }
  };
  auto stageKV = [&](int kt, int c) {
#pragma unroll
    for (int j = 0; j < 2; ++j) {
      const int row = wv * 16 + j * 8 + row8;
      const int sw = (ch8 ^ (row & 7)) << 3;
      const int ldso = (wv * 16 + j * 8) * 64;
      gl16(khb + kt * 4096 + row * 64 + sw, &kh2_s[c][ldso]);
      gl16(klb + kt * 4096 + row * 64 + sw, &kl2_s[c][ldso]);
      gl16(vtb + kt * 64 + (size_t)row * 1024 + sw, &vt2_s[c][ldso]);
    }
  };

  float z1L[4] = {0.f, 0.f, 0.f, 0.f}, z2L[4] = {0.f, 0.f, 0.f, 0.f};

  // drain Q/G loads so vmcnt bookkeeping below is exact
  asm volatile("s_waitcnt vmcnt(0)" ::: "memory");
  __builtin_amdgcn_sched_barrier(0);

  // ---------------- pass 1: z-sums (K-hi only), counted-vmcnt dbuf ----------
  stageK(0, 0);
  for (int kt = 0; kt < 16; ++kt) {
    __builtin_amdgcn_s_barrier();            // A: all waves done reading old buf
    __builtin_amdgcn_sched_barrier(0);
    if (kt < 15) {
      stageK(kt + 1, (kt + 1) & 1);
      asm volatile("s_waitcnt vmcnt(2)" ::: "memory");  // tile kt's 2 loads done
    } else {
      asm volatile("s_waitcnt vmcnt(0)" ::: "memory");
    }
    __builtin_amdgcn_sched_barrier(0);
    __builtin_amdgcn_s_barrier();            // B: all threads' writes visible
    __builtin_amdgcn_sched_barrier(0);

    const ushort* kp = kh2_s[kt & 1];
    f32x4 s1[4], s2[4];
#pragma unroll
    for (int ct = 0; ct < 4; ++ct) {
      f32x4 z = {0.f, 0.f, 0.f, 0.f};
      s1[ct] = z; s2[ct] = z;
#pragma unroll
      for (int ks = 0; ks < 2; ++ks) {
        const u16x8 khf = ldfrag(kp, ct * 16 + lr, ks * 4 + lg);
        s1[ct] = mfma_t<1>(qh[ks], khf, s1[ct]);
        s2[ct] = mfma_t<1>(gh[ks], khf, s2[ct]);
      }
    }
#pragma unroll
    for (int r = 0; r < 4; ++r)
#pragma unroll
      for (int ct = 0; ct < 4; ++ct) {
        z1L[r] += __expf(s1[ct][r] - 16.f);
        z2L[r] += __expf(s2[ct][r] - 64.f);
      }
  }

  float rzr[4];
#pragma unroll
  for (int r = 0; r < 4; ++r) {
    float z1 = z1L[r], z2 = z2L[r];
#pragma unroll
    for (int msk = 1; msk < 16; msk <<= 1) {
      z1 += __shfl_xor(z1, msk);
      z2 += __shfl_xor(z2, msk);
    }
    rzr[r] = 1.f / (z1 * z2);
  }

  // u = q + g, fp16 hi/lo split
  u16x8 uh[2], ul[2];
#pragma unroll
  for (int ks = 0; ks < 2; ++ks)
#pragma unroll
    for (int e = 0; e < 8; ++e) {
      const float u = cvt_back<1>(qh[ks][e]) + gf[ks][e];
      const _Float16 hu = (_Float16)u;
      uh[ks][e] = __builtin_bit_cast(ushort, hu);
      ul[ks][e] = cvt_hi<1>(u - (float)hu);
    }

  f32x4 o[4];
#pragma unroll
  for (int dt = 0; dt < 4; ++dt) { f32x4 z = {0.f, 0.f, 0.f, 0.f}; o[dt] = z; }

  float* wrow = attn + ((size_t)bh * S_ + q0) * S_;
  ushort* wsw = w_s[wv];

  // ---------------- pass 2: exact weights + PV, counted-vmcnt dbuf ----------
  stageKV(0, 0);  // issued before rzr/u consumed it? no deps; pass1 drained vmcnt
  for (int kt = 0; kt < 16; ++kt) {
    __builtin_amdgcn_s_barrier();            // A: all waves done with old buf
    __builtin_amdgcn_sched_barrier(0);
    if (kt == 0) {
      stageKV(1, 1);
      asm volatile("s_waitcnt vmcnt(6)" ::: "memory");   // [st0 6][st1 6] -> st0 done
    } else if (kt < 15) {
      stageKV(kt + 1, (kt + 1) & 1);
      asm volatile("s_waitcnt vmcnt(10)" ::: "memory");  // [stK 6][stores 4][stK+1 6]
    } else {
      asm volatile("s_waitcnt vmcnt(4)" ::: "memory");   // [st15 6][stores 4]
    }
    __builtin_amdgcn_sched_barrier(0);
    __builtin_amdgcn_s_barrier();            // B: all threads' writes visible
    __builtin_amdgcn_sched_barrier(0);

    const int c = kt & 1;
    const ushort* khp = kh2_s[c];
    const ushort* klp = kl2_s[c];
    const ushort* vtp = vt2_s[c];

    f32x4 s12[4];
#pragma unroll
    for (int ct = 0; ct < 4; ++ct) {
      f32x4 z = {0.f, 0.f, 0.f, 0.f};
      s12[ct] = z;
#pragma unroll
      for (int ks = 0; ks < 2; ++ks) {
        const u16x8 khf = ldfrag(khp, ct * 16 + lr, ks * 4 + lg);
        const u16x8 klf = ldfrag(klp, ct * 16 + lr, ks * 4 + lg);
        s12[ct] = mfma_t<1>(uh[ks], khf, s12[ct]);
        s12[ct] = mfma_t<1>(uh[ks], klf, s12[ct]);
        s12[ct] = mfma_t<1>(ul[ks], khf, s12[ct]);
      }
    }
    // weights -> wave-private LDS (fp16, swizzled)
#pragma unroll
    for (int ct = 0; ct < 4; ++ct) {
#pragma unroll
      for (int r = 0; r < 4; ++r) {
        const int rowq = lg * 4 + r;
        const int key = ct * 16 + lr;
        const float wv2 = __expf(s12[ct][r] - 80.f) * rzr[r];
        const int ch = (key >> 3) ^ (rowq & 7);
        wsw[rowq * 64 + ch * 8 + (key & 7)] = cvt_hi<1>(wv2);
      }
    }
    // PV first (MFMA issues early; reads own-wave w_s + block vt tile)
#pragma unroll
    for (int ks = 0; ks < 2; ++ks) {
      const u16x8 af = ldfrag(wsw, lr, ks * 4 + lg);
#pragma unroll
      for (int dt = 0; dt < 4; ++dt) {
        const u16x8 vf = ldfrag(vtp, dt * 16 + lr, ks * 4 + lg);
        o[dt] = mfma_t<1>(af, vf, o[dt]);
      }
    }
    // global fp32 weight store via own-wave LDS transpose (4x dwordx4/thread)
    {
      const int rowq = (lane >> 2) & 15, cc = lane & 3;
#pragma unroll
      for (int j = 0; j < 2; ++j) {
        const int key8 = cc * 16 + j * 8;
        const int ch = (key8 >> 3) ^ (rowq & 7);
        const uint4 wb = *reinterpret_cast<const uint4*>(&wsw[rowq * 64 + ch * 8]);
        const ushort* wp = reinterpret_cast<const ushort*>(&wb);
        float* dst = wrow + (size_t)rowq * S_ + kt * 64 + key8;
        *reinterpret_cast<f4*>(dst) = make_float4(
            cvt_back<1>(wp[0]), cvt_back<1>(wp[1]), cvt_back<1>(wp[2]), cvt_back<1>(wp[3]));
        *reinterpret_cast<f4*>(dst + 4) = make_float4(
            cvt_back<1>(wp[4]), cvt_back<1>(wp[5]), cvt_back<1>(wp[6]), cvt_back<1>(wp[7]));
      }
    }
  }

  // epilogue: ao[b][s][e] fp16
#pragma unroll
  for (int dt = 0; dt < 4; ++dt)
#pragma unroll
    for (int r = 0; r < 4; ++r)
      aoh[((size_t)b * S_ + q0 + lg * 4 + r) * E_ + h * 64 + dt * 16 + lr] =
          cvt_hi<1>(o[dt][r]);
}

extern "C" void kernel_launch(void* const* d_in, const int* in_sizes, int n_in,
                              void* d_out, int out_size, void* d_ws, size_t ws_size,
                              hipStream_t stream) {
  const float* x  = (const float*)d_in[0];
  const float* ge = (const float*)d_in[1];
  const float* Wq = (const float*)d_in[2];
  const float* bq = (const float*)d_in[3];
  const float* Wk = (const float*)d_in[4];
  const float* bk = (const float*)d_in[5];
  const float* Wv = (const float*)d_in[6];
  const float* bv = (const float*)d_in[7];
  const float* Wo = (const float*)d_in[8];
  const float* bo = (const float*)d_in[9];

  float* out  = (float*)d_out;
  float* attn = out + (size_t)B_ * S_ * E_;

  const size_t MSZ = 1024 * 1024;
  ushort* ws16 = (ushort*)d_ws;  // ~74 MB used (ws ~1 GiB per fill counters)
  ushort* Wqf = ws16 + 0 * MSZ;
  ushort* Wkh = ws16 + 1 * MSZ;
  ushort* Wkl = ws16 + 2 * MSZ;
  ushort* Wvf = ws16 + 3 * MSZ;
  ushort* Wof = ws16 + 4 * MSZ;
  ushort* xf  = ws16 + 5 * MSZ;   // fp16 x
  ushort* xbh = ws16 + 9 * MSZ;   // bf16 x hi
  ushort* xbl = ws16 + 13 * MSZ;  // bf16 x lo
  ushort* qh  = ws16 + 17 * MSZ;  // fp16 q (single, pre-scaled) [B,H,S,HD]
  ushort* kh  = ws16 + 21 * MSZ;  // fp16 k hi [B,H,S,HD]
  ushort* kl  = ws16 + 25 * MSZ;  // fp16 k lo
  ushort* vt  = ws16 + 29 * MSZ;  // fp16 v [B,H,HD,S]
  ushort* aoh = ws16 + 33 * MSZ;  // fp16 ao [B,S,E]

  dim3 blk(256);
  hipLaunchKernelGGL(prep_x, dim3(2048), blk, 0, stream, x, xf, xbh, xbl);
  hipLaunchKernelGGL(prep_w, dim3(16, 16, 4), blk, 0, stream, Wq, Wk, Wv, Wo, ws16);

  dim3 ggrid(E_ / 128, (B_ * S_) / 64);
  // Q: 1-term fp16 (pre-scaled 0.125)
  hipLaunchKernelGGL((gemm_mfma<1, 1, 3>), ggrid, blk, 0, stream,
                     xf, nullptr, Wqf, nullptr, bq, 0.125f, qh, nullptr, nullptr);
  // K: 3-term bf16 (denorm-safe splits), output fp16 hi/lo
  hipLaunchKernelGGL((gemm_mfma<3, 0, 1>), ggrid, blk, 0, stream,
                     xbh, xbl, Wkh, Wkl, bk, 1.0f, kh, kl, nullptr);
  // V: 1-term fp16, transposed output
  hipLaunchKernelGGL((gemm_mfma<1, 1, 2>), ggrid, blk, 0, stream,
                     xf, nullptr, Wvf, nullptr, bv, 1.0f, vt, nullptr, nullptr);

  hipLaunchKernelGGL(attn_mfma, dim3(1024), blk, 0, stream,
                     qh, kh, kl, vt, ge, attn, aoh);

  // O: 1-term fp16 -> fp32 out
  hipLaunchKernelGGL((gemm_mfma<1, 1, 0>), ggrid, blk, 0, stream,
                     aoh, nullptr, Wof, nullptr, bo, 1.0f, nullptr, nullptr, out);
}

// Round 12
// 203.400 us; speedup vs baseline: 1.2724x; 1.1787x over previous
//
#include <hip/hip_runtime.h>
#include <math.h>

#define B_ 4
#define S_ 1024
#define E_ 1024
#define H_ 16
#define HD_ 64

typedef float4 f4;
typedef __bf16 bf16x8 __attribute__((ext_vector_type(8)));
typedef _Float16 f16x8 __attribute__((ext_vector_type(8)));
typedef ushort u16x8 __attribute__((ext_vector_type(8)));
typedef float f32x4 __attribute__((ext_vector_type(4)));

// async global->LDS, 16B per lane. LDS dest = wave-uniform base + lane*16.
__device__ __forceinline__ void gl16(const void* g, void* l) {
  __builtin_amdgcn_global_load_lds(
      (__attribute__((address_space(1))) void*)g,
      (__attribute__((address_space(3))) void*)l, 16, 0, 0);
}

template <int MT> __device__ __forceinline__ ushort cvt_hi(float x) {
  if constexpr (MT == 0) return __builtin_bit_cast(ushort, (__bf16)x);
  else return __builtin_bit_cast(ushort, (_Float16)x);
}
template <int MT> __device__ __forceinline__ float cvt_back(ushort h) {
  if constexpr (MT == 0) {
    union { unsigned u; float f; } v; v.u = (unsigned)h << 16; return v.f;
  } else {
    return (float)__builtin_bit_cast(_Float16, h);
  }
}
template <int MT> __device__ __forceinline__ f32x4 mfma_t(u16x8 a, u16x8 b, f32x4 c) {
  if constexpr (MT == 0)
    return __builtin_amdgcn_mfma_f32_16x16x32_bf16(
        __builtin_bit_cast(bf16x8, a), __builtin_bit_cast(bf16x8, b), c, 0, 0, 0);
  else
    return __builtin_amdgcn_mfma_f32_16x16x32_f16(
        __builtin_bit_cast(f16x8, a), __builtin_bit_cast(f16x8, b), c, 0, 0, 0);
}
// frag load from swizzled LDS: 16B at (row, chunk), row stride 64 ushorts.
__device__ __forceinline__ u16x8 ldfrag(const ushort* s, int row, int chunk) {
  return *reinterpret_cast<const u16x8*>(s + row * 64 + ((chunk ^ (row & 7)) << 3));
}
// frag load, row stride 32 ushorts (vt tiles, 4 chunks/row)
__device__ __forceinline__ u16x8 ldfrag32(const ushort* s, int row, int chunk) {
  return *reinterpret_cast<const u16x8*>(s + row * 32 + ((chunk ^ (row & 3)) << 3));
}

// ws16 layout (units of MSZ = 1M ushorts = 2 MB):
// 0:Wqf  1:Wkh 2:Wkl  3:Wvf 4:Wof  5..8:xf  9..12:xbh 13..16:xbl
// 17..20:qh  21..24:kh 25..28:kl  29..32:vt  33..36:aoh

// ---------------------------------------------------------------------------
// prep_x: x fp32 -> fp16 (Q/V path) + bf16 hi/lo (K path, denorm-safe splits)
// ---------------------------------------------------------------------------
__global__ __launch_bounds__(256) void prep_x(
    const float* __restrict__ x, ushort* __restrict__ xf,
    ushort* __restrict__ xbh, ushort* __restrict__ xbl)
{
  const size_t i = ((size_t)blockIdx.x * 256 + threadIdx.x) * 8;
  float v[8];
  *reinterpret_cast<f4*>(v)     = *reinterpret_cast<const f4*>(x + i);
  *reinterpret_cast<f4*>(v + 4) = *reinterpret_cast<const f4*>(x + i + 4);
  unsigned fw[4], hw[4], lw[4];
#pragma unroll
  for (int p = 0; p < 4; ++p) {
    const float a = v[2 * p], b = v[2 * p + 1];
    fw[p] = (unsigned)cvt_hi<1>(a) | ((unsigned)cvt_hi<1>(b) << 16);
    const ushort ha = cvt_hi<0>(a), hb = cvt_hi<0>(b);
    hw[p] = (unsigned)ha | ((unsigned)hb << 16);
    lw[p] = (unsigned)cvt_hi<0>(a - cvt_back<0>(ha)) |
            ((unsigned)cvt_hi<0>(b - cvt_back<0>(hb)) << 16);
  }
  *reinterpret_cast<uint4*>(xf + i)  = make_uint4(fw[0], fw[1], fw[2], fw[3]);
  *reinterpret_cast<uint4*>(xbh + i) = make_uint4(hw[0], hw[1], hw[2], hw[3]);
  *reinterpret_cast<uint4*>(xbl + i) = make_uint4(lw[0], lw[1], lw[2], lw[3]);
}

// ---------------------------------------------------------------------------
// prep_w: W fp32 [k][n] -> transposed Wt[n][k]: Wq/Wv/Wo fp16; Wk bf16 hi/lo.
// ---------------------------------------------------------------------------
__global__ __launch_bounds__(256) void prep_w(
    const float* __restrict__ Wq, const float* __restrict__ Wk,
    const float* __restrict__ Wv, const float* __restrict__ Wo,
    ushort* __restrict__ ws16)
{
  const int MSZ = 1024 * 1024;
  const int mat = blockIdx.z;
  const int n0 = blockIdx.x * 64, k0 = blockIdx.y * 64;
  const float* W = mat == 0 ? Wq : mat == 1 ? Wk : mat == 2 ? Wv : Wo;
  ushort* Oh = ws16 + (mat == 0 ? 0 : mat == 1 ? 1 : mat == 2 ? 3 : 4) * MSZ;
  ushort* Ol = mat == 1 ? ws16 + 2 * MSZ : nullptr;

  __shared__ __align__(16) float tile[64][65];
  const int t = threadIdx.x;
  const int r = t >> 2, cq = t & 3;
#pragma unroll
  for (int j = 0; j < 4; ++j) {
    const f4 v = *reinterpret_cast<const f4*>(&W[(size_t)(k0 + r) * 1024 + n0 + cq * 16 + 4 * j]);
    tile[r][cq * 16 + 4 * j + 0] = v.x;
    tile[r][cq * 16 + 4 * j + 1] = v.y;
    tile[r][cq * 16 + 4 * j + 2] = v.z;
    tile[r][cq * 16 + 4 * j + 3] = v.w;
  }
  __syncthreads();
  unsigned hw[8], lw[8];
#pragma unroll
  for (int p = 0; p < 8; ++p) {
    const float a = tile[cq * 16 + 2 * p][r];
    const float b = tile[cq * 16 + 2 * p + 1][r];
    if (mat == 1) {
      const ushort ha = cvt_hi<0>(a), hb = cvt_hi<0>(b);
      hw[p] = (unsigned)ha | ((unsigned)hb << 16);
      lw[p] = (unsigned)cvt_hi<0>(a - cvt_back<0>(ha)) |
              ((unsigned)cvt_hi<0>(b - cvt_back<0>(hb)) << 16);
    } else {
      hw[p] = (unsigned)cvt_hi<1>(a) | ((unsigned)cvt_hi<1>(b) << 16);
    }
  }
  ushort* dh = Oh + (size_t)(n0 + r) * 1024 + k0 + cq * 16;
  *reinterpret_cast<uint4*>(dh)     = make_uint4(hw[0], hw[1], hw[2], hw[3]);
  *reinterpret_cast<uint4*>(dh + 8) = make_uint4(hw[4], hw[5], hw[6], hw[7]);
  if (Ol) {
    ushort* dl = Ol + (size_t)(n0 + r) * 1024 + k0 + cq * 16;
    *reinterpret_cast<uint4*>(dl)     = make_uint4(lw[0], lw[1], lw[2], lw[3]);
    *reinterpret_cast<uint4*>(dl + 8) = make_uint4(lw[4], lw[5], lw[6], lw[7]);
  }
}

// ---------------------------------------------------------------------------
// MFMA GEMM (R6 structure, single-buffered): C = A @ Wt^T + bias.
// Tile 64(M) x 128(N), BK=64. All staging via global_load_lds.
// ---------------------------------------------------------------------------
template <int TERMS, int MT, int OMODE>
__global__ __launch_bounds__(256) void gemm_mfma(
    const ushort* __restrict__ Ab, const ushort* __restrict__ Abl,
    const ushort* __restrict__ Bhg, const ushort* __restrict__ Blg,
    const float* __restrict__ bias, float scale,
    ushort* __restrict__ Oh, ushort* __restrict__ Ol, float* __restrict__ Of)
{
  const int n0 = blockIdx.x * 128;
  const int m0 = blockIdx.y * 64;
  const int t = threadIdx.x;
  const int wv = t >> 6, lane = t & 63;
  const int lr = lane & 15, lg = lane >> 4;
  const int wm = (wv >> 1) * 32, wn = (wv & 1) * 64;
  const int row8 = lane >> 3, ch8 = lane & 7;

  __shared__ __align__(16) ushort Ah_s[64 * 64];
  __shared__ __align__(16) ushort Al_s[TERMS == 3 ? 64 * 64 : 16];
  __shared__ __align__(16) ushort Bh_s[128 * 64];
  __shared__ __align__(16) ushort Bl_s[TERMS == 3 ? 128 * 64 : 16];
  __shared__ __align__(16) ushort tr_s[OMODE == 2 ? 128 * 72 : 16];

  f32x4 acc[2][4];
#pragma unroll
  for (int mi = 0; mi < 2; ++mi)
#pragma unroll
    for (int ni = 0; ni < 4; ++ni) { f32x4 z = {0.f, 0.f, 0.f, 0.f}; acc[mi][ni] = z; }

  for (int kt = 0; kt < 16; ++kt) {
    const int k0 = kt * 64;
    __syncthreads();
#pragma unroll
    for (int j = 0; j < 4; ++j) {
      const int row = wv * 32 + j * 8 + row8;
      const size_t go = (size_t)(n0 + row) * 1024 + k0 + ((ch8 ^ (row & 7)) << 3);
      gl16(Bhg + go, &Bh_s[(wv * 32 + j * 8) * 64]);
      if constexpr (TERMS == 3) gl16(Blg + go, &Bl_s[(wv * 32 + j * 8) * 64]);
    }
#pragma unroll
    for (int j = 0; j < 2; ++j) {
      const int row = wv * 16 + j * 8 + row8;
      const size_t go = (size_t)(m0 + row) * 1024 + k0 + ((ch8 ^ (row & 7)) << 3);
      gl16(Ab + go, &Ah_s[(wv * 16 + j * 8) * 64]);
      if constexpr (TERMS == 3) gl16(Abl + go, &Al_s[(wv * 16 + j * 8) * 64]);
    }
    __syncthreads();
#pragma unroll
    for (int ks = 0; ks < 2; ++ks) {
      const u16x8 ah0 = ldfrag(Ah_s, wm + lr, ks * 4 + lg);
      const u16x8 ah1 = ldfrag(Ah_s, wm + 16 + lr, ks * 4 + lg);
      u16x8 al0, al1;
      if constexpr (TERMS == 3) {
        al0 = ldfrag(Al_s, wm + lr, ks * 4 + lg);
        al1 = ldfrag(Al_s, wm + 16 + lr, ks * 4 + lg);
      }
#pragma unroll
      for (int ni = 0; ni < 4; ++ni) {
        const u16x8 bh = ldfrag(Bh_s, wn + ni * 16 + lr, ks * 4 + lg);
        acc[0][ni] = mfma_t<MT>(ah0, bh, acc[0][ni]);
        acc[1][ni] = mfma_t<MT>(ah1, bh, acc[1][ni]);
        if constexpr (TERMS == 3) {
          const u16x8 bl = ldfrag(Bl_s, wn + ni * 16 + lr, ks * 4 + lg);
          acc[0][ni] = mfma_t<MT>(ah0, bl, acc[0][ni]);
          acc[1][ni] = mfma_t<MT>(ah1, bl, acc[1][ni]);
          acc[0][ni] = mfma_t<MT>(al0, bh, acc[0][ni]);
          acc[1][ni] = mfma_t<MT>(al1, bh, acc[1][ni]);
        }
      }
    }
  }

  // ---- epilogue ----
  if constexpr (OMODE == 2) {
    __syncthreads();
#pragma unroll
    for (int mi = 0; mi < 2; ++mi)
#pragma unroll
      for (int ni = 0; ni < 4; ++ni)
#pragma unroll
        for (int r = 0; r < 4; ++r) {
          const int n_l = wn + ni * 16 + lr, m_l = wm + mi * 16 + lg * 4 + r;
          tr_s[n_l * 72 + m_l] = cvt_hi<1>(acc[mi][ni][r] + bias[n0 + n_l]);
        }
    __syncthreads();
    const int row = t >> 1, hf = t & 1;
    const int n_g = n0 + row;
    const int h_ = n_g >> 6, hd = n_g & 63;
    const int b_g = m0 >> 10;
    ushort* dst = Oh + ((size_t)(b_g * 16 + h_) * 64 + hd) * 1024 + (m0 & 1023) + hf * 32;
#pragma unroll
    for (int j = 0; j < 4; ++j)
      *reinterpret_cast<uint4*>(dst + 8 * j) =
          *reinterpret_cast<const uint4*>(&tr_s[row * 72 + hf * 32 + 8 * j]);
  } else {
#pragma unroll
    for (int mi = 0; mi < 2; ++mi)
#pragma unroll
      for (int ni = 0; ni < 4; ++ni) {
        const int n = n0 + wn + ni * 16 + lr;
        const float bi = bias[n];
#pragma unroll
        for (int r = 0; r < 4; ++r) {
          const int m = m0 + wm + mi * 16 + lg * 4 + r;
          const float v = (acc[mi][ni][r] + bi) * scale;
          if constexpr (OMODE == 0) {
            Of[(size_t)m * 1024 + n] = v;
          } else {
            const size_t addr =
                ((size_t)((m >> 10) * 16 + (n >> 6)) * 1024 + (m & 1023)) * 64 + (n & 63);
            if constexpr (OMODE == 1) {
              const _Float16 hv = (_Float16)v;
              Oh[addr] = __builtin_bit_cast(ushort, hv);
              Ol[addr] = cvt_hi<1>(v - (float)hv);
            } else {  // OMODE == 3
              Oh[addr] = cvt_hi<1>(v);
            }
          }
        }
      }
  }
}

// ---------------------------------------------------------------------------
// MFMA dual-softmax attention: counted-vmcnt pipeline (R11 scheme) at HIGH
// occupancy: KVBLK=32 -> full dbuf kh/kl/vt = 24KB + w_s 8KB = 32KB LDS ->
// 5 blocks/CU (20 waves). Per-iter: pass1 1 load -> vmcnt(1/0); pass2 3 loads
// + 2 stores -> vmcnt(3/5/2). Stores never waited on. exp/z accumulation
// order identical to R6/R11 -> bit-identical output.
// ---------------------------------------------------------------------------
__global__ __launch_bounds__(256) void attn_mfma(
    const ushort* __restrict__ qh_g, const ushort* __restrict__ kh_g,
    const ushort* __restrict__ kl_g, const ushort* __restrict__ vt_g,
    const float* __restrict__ ge, float* __restrict__ attn,
    ushort* __restrict__ aoh)
{
  __shared__ __align__(16) ushort kh2_s[2][2048];
  __shared__ __align__(16) ushort kl2_s[2][2048];
  __shared__ __align__(16) ushort vt2_s[2][2048];
  __shared__ __align__(16) ushort w_s[4][1024];

  const int bid = blockIdx.x;
  const int wg = (bid & 7) * 128 + (bid >> 3);  // bijective XCD swizzle (1024 = 8*128)
  const int bh = wg >> 4, qb = wg & 15;
  const int b = bh >> 4, h = bh & 15;

  const int t = threadIdx.x;
  const int wv = t >> 6, lane = t & 63;
  const int lr = lane & 15, lg = lane >> 4;
  const int q0 = qb * 64 + wv * 16;

  // Q (fp16, pre-scaled 0.125) + G (fp32 kept for u; fp16-hi for pass 1)
  u16x8 qh[2], gh[2];
  float gf[2][8];
#pragma unroll
  for (int ks = 0; ks < 2; ++ks) {
    const size_t qoff = ((size_t)bh * S_ + q0 + lr) * HD_ + ks * 32 + lg * 8;
    qh[ks] = *reinterpret_cast<const u16x8*>(qh_g + qoff);
    const float* grow = ge + ((size_t)b * S_ + q0 + lr) * HD_ + ks * 32 + lg * 8;
    *reinterpret_cast<f4*>(&gf[ks][0]) = *reinterpret_cast<const f4*>(grow);
    *reinterpret_cast<f4*>(&gf[ks][4]) = *reinterpret_cast<const f4*>(grow + 4);
#pragma unroll
    for (int e = 0; e < 8; ++e) gh[ks][e] = cvt_hi<1>(gf[ks][e]);
  }

  const ushort* khb = kh_g + (size_t)bh * S_ * HD_;
  const ushort* klb = kl_g + (size_t)bh * S_ * HD_;
  const ushort* vtb = vt_g + (size_t)bh * HD_ * S_;

  // per-wave staging geometry (tile = 32 keys x 64 d for K; 64 d x 32 keys V)
  const int krow = wv * 8 + (lane >> 3);           // K tile row (key), 8/wave
  const int ksw  = ((lane & 7) ^ (krow & 7)) << 3; // pre-swizzled source chunk
  const int vrow = wv * 16 + (lane >> 2);          // V tile row (d), 16/wave
  const int vsw  = ((lane & 3) ^ (vrow & 3)) << 3;

  auto stage_kh = [&](int kt, int c) {
    gl16(khb + kt * 2048 + krow * 64 + ksw, &kh2_s[c][wv * 512]);
  };
  auto stage_kl = [&](int kt, int c) {
    gl16(klb + kt * 2048 + krow * 64 + ksw, &kl2_s[c][wv * 512]);
  };
  auto stage_vt = [&](int kt, int c) {
    gl16(vtb + kt * 32 + (size_t)vrow * 1024 + vsw, &vt2_s[c][wv * 512]);
  };

  float z1L[4] = {0.f, 0.f, 0.f, 0.f}, z2L[4] = {0.f, 0.f, 0.f, 0.f};

  // drain Q/G loads so vmcnt bookkeeping below is exact
  asm volatile("s_waitcnt vmcnt(0)" ::: "memory");
  __builtin_amdgcn_sched_barrier(0);

  // ---------------- pass 1: z-sums (K-hi only), counted-vmcnt dbuf ----------
  stage_kh(0, 0);
  for (int kt = 0; kt < 32; ++kt) {
    if (kt < 31) {
      stage_kh(kt + 1, (kt + 1) & 1);
      asm volatile("s_waitcnt vmcnt(1)" ::: "memory");
    } else {
      asm volatile("s_waitcnt vmcnt(0)" ::: "memory");
    }
    __builtin_amdgcn_sched_barrier(0);
    __builtin_amdgcn_s_barrier();   // all waves staged -> tile kt visible
    __builtin_amdgcn_sched_barrier(0);

    const ushort* kp = kh2_s[kt & 1];
    f32x4 s1[2], s2[2];
#pragma unroll
    for (int ct = 0; ct < 2; ++ct) {
      f32x4 z = {0.f, 0.f, 0.f, 0.f};
      s1[ct] = z; s2[ct] = z;
#pragma unroll
      for (int ks = 0; ks < 2; ++ks) {
        const u16x8 khf = ldfrag(kp, ct * 16 + lr, ks * 4 + lg);
        s1[ct] = mfma_t<1>(qh[ks], khf, s1[ct]);
        s2[ct] = mfma_t<1>(gh[ks], khf, s2[ct]);
      }
    }
#pragma unroll
    for (int r = 0; r < 4; ++r)
#pragma unroll
      for (int ct = 0; ct < 2; ++ct) {
        z1L[r] += __expf(s1[ct][r] - 16.f);
        z2L[r] += __expf(s2[ct][r] - 64.f);
      }
    __builtin_amdgcn_s_barrier();   // all waves done reading buf before overwrite
    __builtin_amdgcn_sched_barrier(0);
  }

  float rzr[4];
#pragma unroll
  for (int r = 0; r < 4; ++r) {
    float z1 = z1L[r], z2 = z2L[r];
#pragma unroll
    for (int msk = 1; msk < 16; msk <<= 1) {
      z1 += __shfl_xor(z1, msk);
      z2 += __shfl_xor(z2, msk);
    }
    rzr[r] = 1.f / (z1 * z2);
  }

  // pass-2 prologue loads fly while we finish u on the VALU
  stage_kh(0, 0);
  stage_kl(0, 0);
  stage_vt(0, 0);

  // u = q + g, fp16 hi/lo split
  u16x8 uh[2], ul[2];
#pragma unroll
  for (int ks = 0; ks < 2; ++ks)
#pragma unroll
    for (int e = 0; e < 8; ++e) {
      const float u = cvt_back<1>(qh[ks][e]) + gf[ks][e];
      const _Float16 hu = (_Float16)u;
      uh[ks][e] = __builtin_bit_cast(ushort, hu);
      ul[ks][e] = cvt_hi<1>(u - (float)hu);
    }

  f32x4 o[4];
#pragma unroll
  for (int dt = 0; dt < 4; ++dt) { f32x4 z = {0.f, 0.f, 0.f, 0.f}; o[dt] = z; }

  float* wrow = attn + ((size_t)bh * S_ + q0) * S_;
  ushort* wsw = w_s[wv];

  // ---------------- pass 2: exact weights + PV, counted-vmcnt dbuf ----------
  for (int kt = 0; kt < 32; ++kt) {
    if (kt < 31) {
      stage_kh(kt + 1, (kt + 1) & 1);
      stage_kl(kt + 1, (kt + 1) & 1);
      stage_vt(kt + 1, (kt + 1) & 1);
      // outstanding: [stage kt:3][stores kt-1:2][stage kt+1:3] -> oldest 3 must go
      if (kt == 0) asm volatile("s_waitcnt vmcnt(3)" ::: "memory");
      else         asm volatile("s_waitcnt vmcnt(5)" ::: "memory");
    } else {
      asm volatile("s_waitcnt vmcnt(2)" ::: "memory");  // [stage31:3][stores30:2]
    }
    __builtin_amdgcn_sched_barrier(0);
    __builtin_amdgcn_s_barrier();   // tile kt visible to all waves
    __builtin_amdgcn_sched_barrier(0);

    const int c = kt & 1;
    const ushort* khp = kh2_s[c];
    const ushort* klp = kl2_s[c];
    const ushort* vtp = vt2_s[c];

    f32x4 s12[2];
#pragma unroll
    for (int ct = 0; ct < 2; ++ct) {
      f32x4 z = {0.f, 0.f, 0.f, 0.f};
      s12[ct] = z;
#pragma unroll
      for (int ks = 0; ks < 2; ++ks) {
        const u16x8 khf = ldfrag(khp, ct * 16 + lr, ks * 4 + lg);
        const u16x8 klf = ldfrag(klp, ct * 16 + lr, ks * 4 + lg);
        s12[ct] = mfma_t<1>(uh[ks], khf, s12[ct]);
        s12[ct] = mfma_t<1>(uh[ks], klf, s12[ct]);
        s12[ct] = mfma_t<1>(ul[ks], khf, s12[ct]);
      }
    }
    // weights -> wave-private LDS (fp16, swizzled; keys 0..31 in chunks 0..3)
#pragma unroll
    for (int ct = 0; ct < 2; ++ct) {
#pragma unroll
      for (int r = 0; r < 4; ++r) {
        const int rowq = lg * 4 + r;
        const int key = ct * 16 + lr;
        const float wv2 = __expf(s12[ct][r] - 80.f) * rzr[r];
        const int ch = (key >> 3) ^ (rowq & 7);
        wsw[rowq * 64 + ch * 8 + (key & 7)] = cvt_hi<1>(wv2);
      }
    }
    // PV (MFMA early; w from own-wave LDS, V from block tile)
    {
      const u16x8 af = ldfrag(wsw, lr, lg);
#pragma unroll
      for (int dt = 0; dt < 4; ++dt) {
        const u16x8 vf = ldfrag32(vtp, dt * 16 + lr, lg);
        o[dt] = mfma_t<1>(af, vf, o[dt]);
      }
    }
    // global fp32 weight store via own-wave LDS transpose (2x dwordx4/lane)
    {
      const int rowq = lane >> 2, cc = lane & 3;
      const int ch = cc ^ (rowq & 7);
      const uint4 wb = *reinterpret_cast<const uint4*>(&wsw[rowq * 64 + ch * 8]);
      const ushort* wp = reinterpret_cast<const ushort*>(&wb);
      float* dst = wrow + (size_t)rowq * S_ + kt * 32 + cc * 8;
      *reinterpret_cast<f4*>(dst) = make_float4(
          cvt_back<1>(wp[0]), cvt_back<1>(wp[1]), cvt_back<1>(wp[2]), cvt_back<1>(wp[3]));
      *reinterpret_cast<f4*>(dst + 4) = make_float4(
          cvt_back<1>(wp[4]), cvt_back<1>(wp[5]), cvt_back<1>(wp[6]), cvt_back<1>(wp[7]));
    }
    __builtin_amdgcn_s_barrier();   // all waves done reading buf before overwrite
    __builtin_amdgcn_sched_barrier(0);
  }

  // epilogue: ao[b][s][e] fp16
#pragma unroll
  for (int dt = 0; dt < 4; ++dt)
#pragma unroll
    for (int r = 0; r < 4; ++r)
      aoh[((size_t)b * S_ + q0 + lg * 4 + r) * E_ + h * 64 + dt * 16 + lr] =
          cvt_hi<1>(o[dt][r]);
}

extern "C" void kernel_launch(void* const* d_in, const int* in_sizes, int n_in,
                              void* d_out, int out_size, void* d_ws, size_t ws_size,
                              hipStream_t stream) {
  const float* x  = (const float*)d_in[0];
  const float* ge = (const float*)d_in[1];
  const float* Wq = (const float*)d_in[2];
  const float* bq = (const float*)d_in[3];
  const float* Wk = (const float*)d_in[4];
  const float* bk = (const float*)d_in[5];
  const float* Wv = (const float*)d_in[6];
  const float* bv = (const float*)d_in[7];
  const float* Wo = (const float*)d_in[8];
  const float* bo = (const float*)d_in[9];

  float* out  = (float*)d_out;
  float* attn = out + (size_t)B_ * S_ * E_;

  const size_t MSZ = 1024 * 1024;
  ushort* ws16 = (ushort*)d_ws;  // ~74 MB used (ws ~1 GiB per fill counters)
  ushort* Wqf = ws16 + 0 * MSZ;
  ushort* Wkh = ws16 + 1 * MSZ;
  ushort* Wkl = ws16 + 2 * MSZ;
  ushort* Wvf = ws16 + 3 * MSZ;
  ushort* Wof = ws16 + 4 * MSZ;
  ushort* xf  = ws16 + 5 * MSZ;   // fp16 x
  ushort* xbh = ws16 + 9 * MSZ;   // bf16 x hi
  ushort* xbl = ws16 + 13 * MSZ;  // bf16 x lo
  ushort* qh  = ws16 + 17 * MSZ;  // fp16 q (single, pre-scaled) [B,H,S,HD]
  ushort* kh  = ws16 + 21 * MSZ;  // fp16 k hi [B,H,S,HD]
  ushort* kl  = ws16 + 25 * MSZ;  // fp16 k lo
  ushort* vt  = ws16 + 29 * MSZ;  // fp16 v [B,H,HD,S]
  ushort* aoh = ws16 + 33 * MSZ;  // fp16 ao [B,S,E]

  dim3 blk(256);
  hipLaunchKernelGGL(prep_x, dim3(2048), blk, 0, stream, x, xf, xbh, xbl);
  hipLaunchKernelGGL(prep_w, dim3(16, 16, 4), blk, 0, stream, Wq, Wk, Wv, Wo, ws16);

  dim3 ggrid(E_ / 128, (B_ * S_) / 64);
  // Q: 1-term fp16 (pre-scaled 0.125)
  hipLaunchKernelGGL((gemm_mfma<1, 1, 3>), ggrid, blk, 0, stream,
                     xf, nullptr, Wqf, nullptr, bq, 0.125f, qh, nullptr, nullptr);
  // K: 3-term bf16 (denorm-safe splits), output fp16 hi/lo
  hipLaunchKernelGGL((gemm_mfma<3, 0, 1>), ggrid, blk, 0, stream,
                     xbh, xbl, Wkh, Wkl, bk, 1.0f, kh, kl, nullptr);
  // V: 1-term fp16, transposed output
  hipLaunchKernelGGL((gemm_mfma<1, 1, 2>), ggrid, blk, 0, stream,
                     xf, nullptr, Wvf, nullptr, bv, 1.0f, vt, nullptr, nullptr);

  hipLaunchKernelGGL(attn_mfma, dim3(1024), blk, 0, stream,
                     qh, kh, kl, vt, ge, attn, aoh);

  // O: 1-term fp16 -> fp32 out
  hipLaunchKernelGGL((gemm_mfma<1, 1, 0>), ggrid, blk, 0, stream,
                     aoh, nullptr, Wof, nullptr, bo, 1.0f, nullptr, nullptr, out);
}